// Round 2
// baseline (839.714 us; speedup 1.0000x reference)
//
#include <hip/hip_runtime.h>

typedef unsigned short u16;
typedef __attribute__((ext_vector_type(8))) short short8;
typedef __attribute__((ext_vector_type(4))) float f32x4;
typedef __attribute__((ext_vector_type(4))) unsigned short u16x4;

// ---------- bf16 helpers (OCP bf16 = raw upper 16 bits of fp32, RNE) ----------
__device__ __forceinline__ float bf2f(u16 h){
  unsigned u = ((unsigned)h) << 16; float f; __builtin_memcpy(&f, &u, 4); return f;
}
__device__ __forceinline__ u16 f2bf(float f){
  unsigned u; __builtin_memcpy(&u, &f, 4);
  unsigned r = u + 0x7fffu + ((u >> 16) & 1u);
  return (u16)(r >> 16);
}

// ---------- async global->LDS (16B per lane, wave-uniform LDS base) ----------
__device__ __forceinline__ void glds16(const u16* g, u16* l){
  __builtin_amdgcn_global_load_lds(
      (const __attribute__((address_space(1))) unsigned int*)(const void*)g,
      (__attribute__((address_space(3))) unsigned int*)(void*)l, 16, 0, 0);
}

// ---------- fp32 -> bf16 conversion ----------
__global__ __launch_bounds__(256) void cvt_f32_bf16(const float* __restrict__ src,
                                                    u16* __restrict__ dst, int n4){
  int i = blockIdx.x * 256 + threadIdx.x;
  if (i >= n4) return;
  float4 f = ((const float4*)src)[i];
  u16x4 o; o.x = f2bf(f.x); o.y = f2bf(f.y); o.z = f2bf(f.z); o.w = f2bf(f.w);
  ((u16x4*)dst)[i] = o;
}

// ---------- GEMM C[M,N] = A[M,K] @ B[N,K]^T  (both bf16, K=2048) ----------
// mode 0: N=6144 (Wq|Wk|Wv); Q,K scatter into [B,H,S,DK], V into [B,H,DK,S] (transposed!)
// mode 1: N=2048 (Wo), write fp32 out + bias
#define SWZ(r) ((((r) & 3)) ^ (((r) >> 2) & 3))

__global__ __launch_bounds__(256) void gemm_bt(
    const u16* __restrict__ A, const u16* __restrict__ Bm, int mode,
    u16* __restrict__ qws, u16* __restrict__ kws, u16* __restrict__ vws,
    const float* __restrict__ bq, const float* __restrict__ bk, const float* __restrict__ bv,
    float* __restrict__ outf, const float* __restrict__ bo)
{
  const int K = 2048;
  __shared__ __attribute__((aligned(16))) u16 As[4096];  // 128 rows x 32 (swizzled chunks)
  __shared__ __attribute__((aligned(16))) u16 Bs[4096];

  int tid = threadIdx.x, wave = tid >> 6, lane = tid & 63;
  int quad = lane >> 4, l15 = lane & 15;
  int wm = wave >> 1, wn = wave & 1;

  int r0 = tid >> 2, ph = tid & 3;
  int g0 = ph ^ SWZ(r0);
  int r1 = r0 + 64;
  int g1 = ph ^ SWZ(r1);
  size_t rowA0 = (size_t)blockIdx.y * 128;
  size_t rowB0 = (size_t)blockIdx.x * 128;
  const u16* gA0 = A + (rowA0 + r0) * K + g0 * 8;
  const u16* gA1 = A + (rowA0 + r1) * K + g1 * 8;
  const u16* gB0 = Bm + (rowB0 + r0) * K + g0 * 8;
  const u16* gB1 = Bm + (rowB0 + r1) * K + g1 * 8;
  u16* lA0 = As + wave * 512;
  u16* lA1 = As + 2048 + wave * 512;
  u16* lB0 = Bs + wave * 512;
  u16* lB1 = Bs + 2048 + wave * 512;

  f32x4 acc[4][4];
  #pragma unroll
  for (int i = 0; i < 4; i++)
    #pragma unroll
    for (int j = 0; j < 4; j++) acc[i][j] = f32x4{0.f, 0.f, 0.f, 0.f};

  int aoff[4], boff[4];
  #pragma unroll
  for (int t = 0; t < 4; t++){
    int ra = wm * 64 + t * 16 + l15;
    aoff[t] = ra * 32 + (quad ^ SWZ(ra)) * 8;
    int rb = wn * 64 + t * 16 + l15;
    boff[t] = rb * 32 + (quad ^ SWZ(rb)) * 8;
  }

  for (int k0 = 0; k0 < K; k0 += 32){
    __syncthreads();
    glds16(gA0, lA0); glds16(gA1, lA1);
    glds16(gB0, lB0); glds16(gB1, lB1);
    gA0 += 32; gA1 += 32; gB0 += 32; gB1 += 32;
    __syncthreads();
    short8 af[4], bf[4];
    #pragma unroll
    for (int t = 0; t < 4; t++){
      af[t] = *(const short8*)(As + aoff[t]);
      bf[t] = *(const short8*)(Bs + boff[t]);
    }
    #pragma unroll
    for (int i = 0; i < 4; i++)
      #pragma unroll
      for (int j = 0; j < 4; j++)
        acc[i][j] = __builtin_amdgcn_mfma_f32_16x16x32_bf16(af[i], bf[j], acc[i][j], 0, 0, 0);
  }

  // C layout per 16x16 tile: row m = quad*4 + reg, col n = l15   [verified m89]
  if (mode == 0){
    int col0 = (int)rowB0;                 // 0..6143
    int mat = col0 >> 11;                  // 0=Q 1=K 2=V
    int cm  = col0 & 2047;                 // within-matrix col base = h*128
    const float* bias = (mat == 0) ? bq : (mat == 1) ? bk : bv;
    int b  = (int)(rowA0 >> 11);
    int s0 = (int)(rowA0 & 2047);
    int h  = cm >> 7;
    size_t base = ((size_t)(b * 16 + h)) * 2048 * 128;
    if (mat == 2){
      // V stored TRANSPOSED: [B,H,DK,S]; acc regs r=0..3 are contiguous in s -> packed 8B store
      #pragma unroll
      for (int j = 0; j < 4; j++){
        int d = wn * 64 + j * 16 + l15;
        float bv_ = bias[cm + d];
        #pragma unroll
        for (int i = 0; i < 4; i++){
          int srow = s0 + wm * 64 + i * 16 + quad * 4;
          u16x4 pk;
          #pragma unroll
          for (int r = 0; r < 4; r++) pk[r] = f2bf(acc[i][j][r] + bv_);
          *(u16x4*)(vws + base + (size_t)d * 2048 + srow) = pk;
        }
      }
    } else {
      u16* dst = (mat == 0) ? qws : kws;
      #pragma unroll
      for (int j = 0; j < 4; j++){
        int d = wn * 64 + j * 16 + l15;
        float bv_ = bias[cm + d];
        #pragma unroll
        for (int i = 0; i < 4; i++){
          int srow = s0 + wm * 64 + i * 16 + quad * 4;
          #pragma unroll
          for (int r = 0; r < 4; r++)
            dst[base + (size_t)(srow + r) * 128 + d] = f2bf(acc[i][j][r] + bv_);
        }
      }
    }
  } else {
    int col0 = (int)rowB0;
    #pragma unroll
    for (int j = 0; j < 4; j++){
      int c = col0 + wn * 64 + j * 16 + l15;
      float bo_ = bo[c];
      #pragma unroll
      for (int i = 0; i < 4; i++){
        int rg = (int)rowA0 + wm * 64 + i * 16 + quad * 4;
        #pragma unroll
        for (int r = 0; r < 4; r++)
          outf[(size_t)(rg + r) * 2048 + c] = acc[i][j][r] + bo_;
      }
    }
  }
}

// ---------- RoPE in-place on Q,K  ([B*H, S, 128] bf16) ----------
__global__ __launch_bounds__(256) void rope_qk(u16* __restrict__ q, u16* __restrict__ k){
  int tid = blockIdx.x * 256 + threadIdx.x;   // B*H*S*64 threads
  int j  = tid & 63;
  int s  = (tid >> 6) & 2047;
  int bh = tid >> 17;
  size_t base = ((size_t)bh * 2048 + (size_t)s) * 128;
  float inv = __expf((float)j * -0.14391156831212788f);  // ln(10000)/64
  float th = (float)s * inv;
  float sn, cs; __sincosf(th, &sn, &cs);
  float a = bf2f(q[base + j]), b = bf2f(q[base + j + 64]);
  q[base + j]      = f2bf(a * cs - b * sn);
  q[base + j + 64] = f2bf(b * cs + a * sn);
  a = bf2f(k[base + j]); b = bf2f(k[base + j + 64]);
  k[base + j]      = f2bf(a * cs - b * sn);
  k[base + j + 64] = f2bf(b * cs + a * sn);
}

// ---------- causal flash attention (barrier-free: 4 independent waves/block) ----------
// grid (32, 32 bh); wave w of block bx owns q rows [qt*16, qt*16+16), qt=(31-bx)*4+w.
// K in [B,H,S,DK]; V pre-transposed [B,H,DK,S] -> both QK^T and PV B-fragments are
// contiguous short8 global loads. P transposes through wave-private LDS (m120 pattern).
__global__ __launch_bounds__(256) void flash(
    const u16* __restrict__ Q, const u16* __restrict__ Km, const u16* __restrict__ VT,
    u16* __restrict__ O)
{
  __shared__ __attribute__((aligned(16))) u16 PL[4 * 16 * 72]; // per-wave [q=16][kv pad 72]
  const float scale = 0.08838834764831845f;   // 1/sqrt(128)

  int bh = blockIdx.y;
  int tid = threadIdx.x, wave = tid >> 6, lane = tid & 63;
  int quad = lane >> 4, l15 = lane & 15;
  int qt = (31 - (int)blockIdx.x) * 4 + wave;  // long waves start first
  int qw = qt * 16;

  const u16* Qb = Q  + (size_t)bh * 2048 * 128;
  const u16* Kb = Km + (size_t)bh * 2048 * 128;
  const u16* Vb = VT + (size_t)bh * 2048 * 128;   // [d=128][s=2048]
  u16* PW = PL + wave * (16 * 72);

  short8 qf[4];
  {
    const u16* qr = Qb + (size_t)(qw + l15) * 128 + quad * 8;
    #pragma unroll
    for (int c = 0; c < 4; c++) qf[c] = *(const short8*)(qr + c * 32);
  }

  float mr[4], lr[4]; f32x4 o[8];
  #pragma unroll
  for (int r = 0; r < 4; r++){ mr[r] = -1e30f; lr[r] = 0.f; }
  #pragma unroll
  for (int blk = 0; blk < 8; blk++) o[blk] = f32x4{0.f, 0.f, 0.f, 0.f};

  for (int k0 = 0; k0 <= qw + 15; k0 += 64){
    int smax = (qw + 15 - k0) >> 4; if (smax > 3) smax = 3;
    float sreg[4][4];
    #pragma unroll
    for (int s = 0; s < 4; s++){
      if (s <= smax){
        f32x4 accs = f32x4{0.f, 0.f, 0.f, 0.f};
        const u16* kr = Kb + (size_t)(k0 + s * 16 + l15) * 128 + quad * 8;
        #pragma unroll
        for (int c = 0; c < 4; c++){
          short8 kf = *(const short8*)(kr + c * 32);
          accs = __builtin_amdgcn_mfma_f32_16x16x32_bf16(qf[c], kf, accs, 0, 0, 0);
        }
        int kvcol = k0 + s * 16 + l15;
        bool diag = (k0 + s * 16 + 15) > qw;
        #pragma unroll
        for (int r = 0; r < 4; r++){
          float v = accs[r] * scale;
          if (diag && (kvcol > qw + quad * 4 + r)) v = -1e30f;
          sreg[s][r] = v;
        }
      }
    }
    float mx[4];
    #pragma unroll
    for (int r = 0; r < 4; r++){
      float x = sreg[0][r];
      #pragma unroll
      for (int s = 1; s < 4; s++) if (s <= smax) x = fmaxf(x, sreg[s][r]);
      x = fmaxf(x, __shfl_xor(x, 1));
      x = fmaxf(x, __shfl_xor(x, 2));
      x = fmaxf(x, __shfl_xor(x, 4));
      x = fmaxf(x, __shfl_xor(x, 8));
      mx[r] = x;
    }
    float alpha[4];
    #pragma unroll
    for (int r = 0; r < 4; r++){
      float mn = fmaxf(mr[r], mx[r]);
      alpha[r] = __expf(mr[r] - mn);
      mr[r] = mn;
    }
    float lsum[4] = {0.f, 0.f, 0.f, 0.f};
    int prow = (quad * 4) * 72;
    #pragma unroll
    for (int s = 0; s < 4; s++){
      if (s <= smax){
        #pragma unroll
        for (int r = 0; r < 4; r++){
          float p = __expf(sreg[s][r] - mr[r]);
          lsum[r] += p;
          PW[prow + r * 72 + s * 16 + l15] = f2bf(p);
        }
      }
    }
    if (!(smax & 1)){   // zero-fill partner sub-tile of the active 32-chunk
      #pragma unroll
      for (int r = 0; r < 4; r++) PW[prow + r * 72 + (smax + 1) * 16 + l15] = 0;
    }
    #pragma unroll
    for (int r = 0; r < 4; r++){
      float sv = lsum[r];
      sv += __shfl_xor(sv, 1); sv += __shfl_xor(sv, 2);
      sv += __shfl_xor(sv, 4); sv += __shfl_xor(sv, 8);
      lr[r] = lr[r] * alpha[r] + sv;
    }
    #pragma unroll
    for (int blk = 0; blk < 8; blk++){
      o[blk][0] *= alpha[0]; o[blk][1] *= alpha[1];
      o[blk][2] *= alpha[2]; o[blk][3] *= alpha[3];
    }
    __builtin_amdgcn_s_waitcnt(0xC07F);   // lgkmcnt(0): wave-private P visible
    int nch = (smax >> 1) + 1;
    #pragma unroll
    for (int c2 = 0; c2 < 2; c2++){
      if (c2 < nch){
        short8 pf = *(const short8*)(PW + l15 * 72 + c2 * 32 + quad * 8);
        const u16* vg = Vb + (size_t)l15 * 2048 + k0 + c2 * 32 + quad * 8;
        #pragma unroll
        for (int blk = 0; blk < 8; blk++){
          short8 vf = *(const short8*)(vg + (size_t)blk * 16 * 2048);
          o[blk] = __builtin_amdgcn_mfma_f32_16x16x32_bf16(pf, vf, o[blk], 0, 0, 0);
        }
      }
    }
  }

  int b = bh >> 4, h = bh & 15;
  float inv[4];
  #pragma unroll
  for (int r = 0; r < 4; r++) inv[r] = 1.0f / lr[r];
  #pragma unroll
  for (int blk = 0; blk < 8; blk++){
    int d = h * 128 + blk * 16 + l15;
    #pragma unroll
    for (int r = 0; r < 4; r++){
      int srow = qw + quad * 4 + r;
      O[((size_t)(b * 2048 + srow)) * 2048 + d] = f2bf(o[blk][r] * inv[r]);
    }
  }
}

// ---------- launcher ----------
extern "C" void kernel_launch(void* const* d_in, const int* in_sizes, int n_in,
                              void* d_out, int out_size, void* d_ws, size_t ws_size,
                              hipStream_t stream)
{
  const float* x  = (const float*)d_in[0];
  // d_in[1] = causal mask, structurally known -> ignored
  const float* Wq = (const float*)d_in[2];
  const float* bq = (const float*)d_in[3];
  const float* Wk = (const float*)d_in[4];
  const float* bk = (const float*)d_in[5];
  const float* Wv = (const float*)d_in[6];
  const float* bv = (const float*)d_in[7];
  const float* Wo = (const float*)d_in[8];
  const float* bo = (const float*)d_in[9];
  float* out = (float*)d_out;

  char* ws = (char*)d_ws;
  u16* xb   = (u16*)(ws);                    // [4096][2048]        16.78 MB
  u16* wcat = (u16*)(ws + 16777216);         // [6144][2048] Wq|Wk|Wv 25.17 MB
  u16* wob  = (u16*)(ws + 41943040);         // [2048][2048]         8.39 MB
  u16* qws  = (u16*)(ws + 50331648);         // [32][2048][128]     16.78 MB
  u16* kws  = (u16*)(ws + 67108864);
  u16* vws  = (u16*)(ws + 83886080);         // [32][128][2048] V^T
  u16* attn = (u16*)(ws + 100663296);        // [4096][2048]        16.78 MB

  const int DD = 2048 * 2048;

  cvt_f32_bf16<<<8192, 256, 0, stream>>>(x,  xb,   (2 * 2048 * 2048) / 4);
  cvt_f32_bf16<<<4096, 256, 0, stream>>>(Wq, wcat,          DD / 4);
  cvt_f32_bf16<<<4096, 256, 0, stream>>>(Wk, wcat + DD,     DD / 4);
  cvt_f32_bf16<<<4096, 256, 0, stream>>>(Wv, wcat + 2 * DD, DD / 4);
  cvt_f32_bf16<<<4096, 256, 0, stream>>>(Wo, wob,           DD / 4);

  gemm_bt<<<dim3(48, 32), 256, 0, stream>>>(xb, wcat, 0, qws, kws, vws,
                                            bq, bk, bv, nullptr, nullptr);
  rope_qk<<<16384, 256, 0, stream>>>(qws, kws);
  flash<<<dim3(32, 32), 256, 0, stream>>>(qws, kws, vws, attn);
  gemm_bt<<<dim3(16, 32), 256, 0, stream>>>(attn, wob, 1, nullptr, nullptr, nullptr,
                                            nullptr, nullptr, nullptr, out, bo);
}

// Round 3
// 498.562 us; speedup vs baseline: 1.6843x; 1.6843x over previous
//
#include <hip/hip_runtime.h>

typedef unsigned short u16;
typedef __attribute__((ext_vector_type(8))) short short8;
typedef __attribute__((ext_vector_type(4))) float f32x4;
typedef __attribute__((ext_vector_type(4))) unsigned short u16x4;

// ---------- bf16 helpers (OCP bf16 = raw upper 16 bits of fp32, RNE) ----------
__device__ __forceinline__ float bf2f(u16 h){
  unsigned u = ((unsigned)h) << 16; float f; __builtin_memcpy(&f, &u, 4); return f;
}
__device__ __forceinline__ u16 f2bf(float f){
  unsigned u; __builtin_memcpy(&u, &f, 4);
  unsigned r = u + 0x7fffu + ((u >> 16) & 1u);
  return (u16)(r >> 16);
}

// ---------- async global->LDS (16B per lane, wave-uniform LDS base) ----------
__device__ __forceinline__ void glds16(const u16* g, u16* l){
  __builtin_amdgcn_global_load_lds(
      (const __attribute__((address_space(1))) unsigned int*)(const void*)g,
      (__attribute__((address_space(3))) unsigned int*)(void*)l, 16, 0, 0);
}

// ---------- fp32 -> bf16 conversion ----------
__global__ __launch_bounds__(256) void cvt_f32_bf16(const float* __restrict__ src,
                                                    u16* __restrict__ dst, int n4){
  int i = blockIdx.x * 256 + threadIdx.x;
  if (i >= n4) return;
  float4 f = ((const float4*)src)[i];
  u16x4 o; o.x = f2bf(f.x); o.y = f2bf(f.y); o.z = f2bf(f.z); o.w = f2bf(f.w);
  ((u16x4*)dst)[i] = o;
}

// ---------- GEMM C[M,N] = A[M,K] @ B[N,K]^T  (both bf16, K=2048) ----------
// mode 0: N=6144 (Wq|Wk|Wv); Q,K scatter into [B,H,S,DK], V into [B,H,DK,S] (transposed!)
// mode 1: N=2048 (Wo), write fp32 out + bias
#define SWZ(r) ((((r) & 3)) ^ (((r) >> 2) & 3))

__global__ __launch_bounds__(256) void gemm_bt(
    const u16* __restrict__ A, const u16* __restrict__ Bm, int mode,
    u16* __restrict__ qws, u16* __restrict__ kws, u16* __restrict__ vws,
    const float* __restrict__ bq, const float* __restrict__ bk, const float* __restrict__ bv,
    float* __restrict__ outf, const float* __restrict__ bo)
{
  const int K = 2048;
  __shared__ __attribute__((aligned(16))) u16 As[4096];
  __shared__ __attribute__((aligned(16))) u16 Bs[4096];

  int tid = threadIdx.x, wave = tid >> 6, lane = tid & 63;
  int quad = lane >> 4, l15 = lane & 15;
  int wm = wave >> 1, wn = wave & 1;

  int r0 = tid >> 2, ph = tid & 3;
  int g0 = ph ^ SWZ(r0);
  int r1 = r0 + 64;
  int g1 = ph ^ SWZ(r1);
  size_t rowA0 = (size_t)blockIdx.y * 128;
  size_t rowB0 = (size_t)blockIdx.x * 128;
  const u16* gA0 = A + (rowA0 + r0) * K + g0 * 8;
  const u16* gA1 = A + (rowA0 + r1) * K + g1 * 8;
  const u16* gB0 = Bm + (rowB0 + r0) * K + g0 * 8;
  const u16* gB1 = Bm + (rowB0 + r1) * K + g1 * 8;
  u16* lA0 = As + wave * 512;
  u16* lA1 = As + 2048 + wave * 512;
  u16* lB0 = Bs + wave * 512;
  u16* lB1 = Bs + 2048 + wave * 512;

  f32x4 acc[4][4];
  #pragma unroll
  for (int i = 0; i < 4; i++)
    #pragma unroll
    for (int j = 0; j < 4; j++) acc[i][j] = f32x4{0.f, 0.f, 0.f, 0.f};

  int aoff[4], boff[4];
  #pragma unroll
  for (int t = 0; t < 4; t++){
    int ra = wm * 64 + t * 16 + l15;
    aoff[t] = ra * 32 + (quad ^ SWZ(ra)) * 8;
    int rb = wn * 64 + t * 16 + l15;
    boff[t] = rb * 32 + (quad ^ SWZ(rb)) * 8;
  }

  for (int k0 = 0; k0 < K; k0 += 32){
    __syncthreads();
    glds16(gA0, lA0); glds16(gA1, lA1);
    glds16(gB0, lB0); glds16(gB1, lB1);
    gA0 += 32; gA1 += 32; gB0 += 32; gB1 += 32;
    __syncthreads();
    short8 af[4], bf[4];
    #pragma unroll
    for (int t = 0; t < 4; t++){
      af[t] = *(const short8*)(As + aoff[t]);
      bf[t] = *(const short8*)(Bs + boff[t]);
    }
    #pragma unroll
    for (int i = 0; i < 4; i++)
      #pragma unroll
      for (int j = 0; j < 4; j++)
        acc[i][j] = __builtin_amdgcn_mfma_f32_16x16x32_bf16(af[i], bf[j], acc[i][j], 0, 0, 0);
  }

  if (mode == 0){
    int col0 = (int)rowB0;
    int mat = col0 >> 11;
    int cm  = col0 & 2047;
    const float* bias = (mat == 0) ? bq : (mat == 1) ? bk : bv;
    int b  = (int)(rowA0 >> 11);
    int s0 = (int)(rowA0 & 2047);
    int h  = cm >> 7;
    size_t base = ((size_t)(b * 16 + h)) * 2048 * 128;
    if (mat == 2){
      // V stored TRANSPOSED: [B,H,DK,S]
      #pragma unroll
      for (int j = 0; j < 4; j++){
        int d = wn * 64 + j * 16 + l15;
        float bv_ = bias[cm + d];
        #pragma unroll
        for (int i = 0; i < 4; i++){
          int srow = s0 + wm * 64 + i * 16 + quad * 4;
          u16x4 pk;
          #pragma unroll
          for (int r = 0; r < 4; r++) pk[r] = f2bf(acc[i][j][r] + bv_);
          *(u16x4*)(vws + base + (size_t)d * 2048 + srow) = pk;
        }
      }
    } else {
      u16* dst = (mat == 0) ? qws : kws;
      #pragma unroll
      for (int j = 0; j < 4; j++){
        int d = wn * 64 + j * 16 + l15;
        float bv_ = bias[cm + d];
        #pragma unroll
        for (int i = 0; i < 4; i++){
          int srow = s0 + wm * 64 + i * 16 + quad * 4;
          #pragma unroll
          for (int r = 0; r < 4; r++)
            dst[base + (size_t)(srow + r) * 128 + d] = f2bf(acc[i][j][r] + bv_);
        }
      }
    }
  } else {
    int col0 = (int)rowB0;
    #pragma unroll
    for (int j = 0; j < 4; j++){
      int c = col0 + wn * 64 + j * 16 + l15;
      float bo_ = bo[c];
      #pragma unroll
      for (int i = 0; i < 4; i++){
        int rg = (int)rowA0 + wm * 64 + i * 16 + quad * 4;
        #pragma unroll
        for (int r = 0; r < 4; r++)
          outf[(size_t)(rg + r) * 2048 + c] = acc[i][j][r] + bo_;
      }
    }
  }
}

// ---------- RoPE in-place on Q,K  ([B*H, S, 128] bf16) ----------
__global__ __launch_bounds__(256) void rope_qk(u16* __restrict__ q, u16* __restrict__ k){
  int tid = blockIdx.x * 256 + threadIdx.x;
  int j  = tid & 63;
  int s  = (tid >> 6) & 2047;
  int bh = tid >> 17;
  size_t base = ((size_t)bh * 2048 + (size_t)s) * 128;
  float inv = __expf((float)j * -0.14391156831212788f);
  float th = (float)s * inv;
  float sn, cs; __sincosf(th, &sn, &cs);
  float a = bf2f(q[base + j]), b = bf2f(q[base + j + 64]);
  q[base + j]      = f2bf(a * cs - b * sn);
  q[base + j + 64] = f2bf(b * cs + a * sn);
  a = bf2f(k[base + j]); b = bf2f(k[base + j + 64]);
  k[base + j]      = f2bf(a * cs - b * sn);
  k[base + j + 64] = f2bf(b * cs + a * sn);
}

// ---------- causal flash attention, block-cooperative ----------
// grid (16, 32 bh); block 256 = 4 waves; block owns 128 q rows (qb = 15-bx, long first),
// wave w owns rows [qb*128 + w*32, +32) as 2 m-tiles. KV-tile 64: K [64][128] and
// V^T [128][64] staged in LDS via global_load_lds with XOR chunk swizzle (2-way reads).
// P transposes through wave-private LDS slab (stride 72). Fully-masked rows self-correct
// via alpha=exp(-1e30 - m_new) = 0 once real data arrives.
__global__ __launch_bounds__(256, 2) void flash(
    const u16* __restrict__ Q, const u16* __restrict__ Km, const u16* __restrict__ VT,
    u16* __restrict__ O)
{
  __shared__ __attribute__((aligned(16))) u16 Ks[64 * 128];    // 16 KB
  __shared__ __attribute__((aligned(16))) u16 Vs[128 * 64];    // 16 KB  (V^T: [d][kv])
  __shared__ __attribute__((aligned(16))) u16 PL[4 * 32 * 72]; // 18 KB per-wave P
  const float scale = 0.08838834764831845f;   // 1/sqrt(128)

  int bh = blockIdx.y;
  int qb = 15 - (int)blockIdx.x;
  int tid = threadIdx.x, wave = tid >> 6, lane = tid & 63;
  int quad = lane >> 4, l15 = lane & 15;
  int qw = qb * 128 + wave * 32;

  const u16* Qb = Q  + (size_t)bh * 2048 * 128;
  const u16* Kb = Km + (size_t)bh * 2048 * 128;
  const u16* Vb = VT + (size_t)bh * 2048 * 128;   // [d=128][s=2048]
  u16* PW = PL + wave * (32 * 72);

  // Q fragments: 2 m-tiles x 4 k-chunks
  short8 qf[2][4];
  #pragma unroll
  for (int m = 0; m < 2; m++){
    const u16* qr = Qb + (size_t)(qw + m * 16 + l15) * 128 + quad * 8;
    #pragma unroll
    for (int c = 0; c < 4; c++) qf[m][c] = *(const short8*)(qr + c * 32);
  }

  // staging pointers (4 rounds each for K and V^T)
  const u16* gK[4]; const u16* gV[4]; u16* lK[4]; u16* lV[4];
  #pragma unroll
  for (int r = 0; r < 4; r++){
    int ci = r * 256 + wave * 64 + lane;
    int krow = ci >> 4, kphys = ci & 15;
    int klog = kphys ^ (krow & 15);
    gK[r] = Kb + (size_t)krow * 128 + klog * 8;
    lK[r] = Ks + (size_t)(r * 256 + wave * 64) * 8;
    int vd = ci >> 3, vphys = ci & 7;
    int vlog = vphys ^ (vd & 7);
    gV[r] = Vb + (size_t)vd * 2048 + vlog * 8;
    lV[r] = Vs + (size_t)(r * 256 + wave * 64) * 8;
  }

  float mr[2][4], lr[2][4]; f32x4 o[2][8];
  #pragma unroll
  for (int m = 0; m < 2; m++)
    #pragma unroll
    for (int r = 0; r < 4; r++){ mr[m][r] = -1e30f; lr[m][r] = 0.f; }
  #pragma unroll
  for (int m = 0; m < 2; m++)
    #pragma unroll
    for (int blk = 0; blk < 8; blk++) o[m][blk] = f32x4{0.f, 0.f, 0.f, 0.f};

  int kvend = qb * 128 + 128;
  for (int k0 = 0; k0 < kvend; k0 += 64){
    __syncthreads();
    #pragma unroll
    for (int r = 0; r < 4; r++){ glds16(gK[r], lK[r]); glds16(gV[r], lV[r]); }
    #pragma unroll
    for (int r = 0; r < 4; r++){ gK[r] += 64 * 128; gV[r] += 64; }
    __syncthreads();

    int rel = qw + 31 - k0;
    if (rel >= 0){
      int smax = rel >> 4; if (smax > 3) smax = 3;
      float sreg[2][4][4];
      #pragma unroll
      for (int t = 0; t < 4; t++){
        if (t <= smax){
          short8 kf[4];
          #pragma unroll
          for (int c = 0; c < 4; c++)
            kf[c] = *(const short8*)(Ks + (t * 16 + l15) * 128 + (((c * 4 + quad) ^ l15) * 8));
          #pragma unroll
          for (int m = 0; m < 2; m++){
            f32x4 a = f32x4{0.f, 0.f, 0.f, 0.f};
            #pragma unroll
            for (int c = 0; c < 4; c++)
              a = __builtin_amdgcn_mfma_f32_16x16x32_bf16(qf[m][c], kf[c], a, 0, 0, 0);
            int kvcol = k0 + t * 16 + l15;
            #pragma unroll
            for (int r = 0; r < 4; r++){
              float v = a[r] * scale;
              int row = qw + m * 16 + quad * 4 + r;
              if (kvcol > row) v = -1e30f;
              sreg[m][t][r] = v;
            }
          }
        }
      }
      float alpha[2][4];
      #pragma unroll
      for (int m = 0; m < 2; m++){
        #pragma unroll
        for (int r = 0; r < 4; r++){
          float x = sreg[m][0][r];
          #pragma unroll
          for (int t = 1; t < 4; t++) if (t <= smax) x = fmaxf(x, sreg[m][t][r]);
          x = fmaxf(x, __shfl_xor(x, 1));
          x = fmaxf(x, __shfl_xor(x, 2));
          x = fmaxf(x, __shfl_xor(x, 4));
          x = fmaxf(x, __shfl_xor(x, 8));
          float mn = fmaxf(mr[m][r], x);
          alpha[m][r] = __expf(mr[m][r] - mn);
          mr[m][r] = mn;
        }
      }
      float lsum[2][4];
      #pragma unroll
      for (int m = 0; m < 2; m++)
        #pragma unroll
        for (int r = 0; r < 4; r++) lsum[m][r] = 0.f;
      #pragma unroll
      for (int t = 0; t < 4; t++){
        if (t <= smax){
          #pragma unroll
          for (int m = 0; m < 2; m++)
            #pragma unroll
            for (int r = 0; r < 4; r++){
              float p = __expf(sreg[m][t][r] - mr[m][r]);
              lsum[m][r] += p;
              PW[(m * 16 + quad * 4 + r) * 72 + t * 16 + l15] = f2bf(p);
            }
        }
      }
      if (!(smax & 1)){   // complete the half-written 32-kv chunk with zeros
        #pragma unroll
        for (int m = 0; m < 2; m++)
          #pragma unroll
          for (int r = 0; r < 4; r++)
            PW[(m * 16 + quad * 4 + r) * 72 + (smax + 1) * 16 + l15] = 0;
      }
      #pragma unroll
      for (int m = 0; m < 2; m++)
        #pragma unroll
        for (int r = 0; r < 4; r++){
          float sv = lsum[m][r];
          sv += __shfl_xor(sv, 1); sv += __shfl_xor(sv, 2);
          sv += __shfl_xor(sv, 4); sv += __shfl_xor(sv, 8);
          lr[m][r] = lr[m][r] * alpha[m][r] + sv;
        }
      #pragma unroll
      for (int m = 0; m < 2; m++)
        #pragma unroll
        for (int blk = 0; blk < 8; blk++){
          o[m][blk][0] *= alpha[m][0]; o[m][blk][1] *= alpha[m][1];
          o[m][blk][2] *= alpha[m][2]; o[m][blk][3] *= alpha[m][3];
        }
      __builtin_amdgcn_s_waitcnt(0xC07F);   // lgkmcnt(0): own-wave P writes visible
      int nch = (smax >> 1) + 1;
      #pragma unroll
      for (int c2 = 0; c2 < 2; c2++){
        if (c2 < nch){
          short8 pf[2];
          #pragma unroll
          for (int m = 0; m < 2; m++)
            pf[m] = *(const short8*)(PW + (m * 16 + l15) * 72 + c2 * 32 + quad * 8);
          #pragma unroll
          for (int blk = 0; blk < 8; blk++){
            int d = blk * 16 + l15;
            short8 vf = *(const short8*)(Vs + d * 64 + (((c2 * 4 + quad) ^ (l15 & 7)) * 8));
            #pragma unroll
            for (int m = 0; m < 2; m++)
              o[m][blk] = __builtin_amdgcn_mfma_f32_16x16x32_bf16(pf[m], vf, o[m][blk], 0, 0, 0);
          }
        }
      }
    }
  }

  int b = bh >> 4, h = bh & 15;
  #pragma unroll
  for (int m = 0; m < 2; m++){
    float inv[4];
    #pragma unroll
    for (int r = 0; r < 4; r++) inv[r] = 1.0f / lr[m][r];
    #pragma unroll
    for (int blk = 0; blk < 8; blk++){
      int d = h * 128 + blk * 16 + l15;
      #pragma unroll
      for (int r = 0; r < 4; r++){
        int srow = qw + m * 16 + quad * 4 + r;
        O[((size_t)(b * 2048 + srow)) * 2048 + d] = f2bf(o[m][blk][r] * inv[r]);
      }
    }
  }
}

// ---------- launcher ----------
extern "C" void kernel_launch(void* const* d_in, const int* in_sizes, int n_in,
                              void* d_out, int out_size, void* d_ws, size_t ws_size,
                              hipStream_t stream)
{
  const float* x  = (const float*)d_in[0];
  const float* Wq = (const float*)d_in[2];
  const float* bq = (const float*)d_in[3];
  const float* Wk = (const float*)d_in[4];
  const float* bk = (const float*)d_in[5];
  const float* Wv = (const float*)d_in[6];
  const float* bv = (const float*)d_in[7];
  const float* Wo = (const float*)d_in[8];
  const float* bo = (const float*)d_in[9];
  float* out = (float*)d_out;

  char* ws = (char*)d_ws;
  u16* xb   = (u16*)(ws);
  u16* wcat = (u16*)(ws + 16777216);
  u16* wob  = (u16*)(ws + 41943040);
  u16* qws  = (u16*)(ws + 50331648);
  u16* kws  = (u16*)(ws + 67108864);
  u16* vws  = (u16*)(ws + 83886080);         // [32][128][2048] V^T
  u16* attn = (u16*)(ws + 100663296);

  const int DD = 2048 * 2048;

  cvt_f32_bf16<<<8192, 256, 0, stream>>>(x,  xb,   (2 * 2048 * 2048) / 4);
  cvt_f32_bf16<<<4096, 256, 0, stream>>>(Wq, wcat,          DD / 4);
  cvt_f32_bf16<<<4096, 256, 0, stream>>>(Wk, wcat + DD,     DD / 4);
  cvt_f32_bf16<<<4096, 256, 0, stream>>>(Wv, wcat + 2 * DD, DD / 4);
  cvt_f32_bf16<<<4096, 256, 0, stream>>>(Wo, wob,           DD / 4);

  gemm_bt<<<dim3(48, 32), 256, 0, stream>>>(xb, wcat, 0, qws, kws, vws,
                                            bq, bk, bv, nullptr, nullptr);
  rope_qk<<<16384, 256, 0, stream>>>(qws, kws);
  flash<<<dim3(16, 32), 256, 0, stream>>>(qws, kws, vws, attn);
  gemm_bt<<<dim3(16, 32), 256, 0, stream>>>(attn, wob, 1, nullptr, nullptr, nullptr,
                                            nullptr, nullptr, nullptr, out, bo);
}